// Round 10
// baseline (66.484 us; speedup 1.0000x reference)
//
#include <hip/hip_runtime.h>

typedef _Float16 f16_t;
typedef f16_t f16x8 __attribute__((ext_vector_type(8)));
typedef f16_t f16x4 __attribute__((ext_vector_type(4)));
typedef float f32x4 __attribute__((ext_vector_type(4)));

#define R_ 32
#define NTRAJ 256
#define TSTEPS 128
#define PDIM 17
#define KTRUE 289
#define KSEG 320          // padded K (5 x 64)
#define NKT 5             // K-tiles
#define MDIM 1024
#define CHS 16            // steps per chain wave
#define NCH 8             // chunks per trajectory

#define SBAR() __builtin_amdgcn_s_barrier()
#define SCHED0() __builtin_amdgcn_sched_barrier(0)
#define PRIO(x) __builtin_amdgcn_s_setprio(x)

// ---------------------------------------------------------------------------
// Merged prep kernel. Blocks [0,128): Ct[il][pq] (fp16, K-contig).
// Blocks [128, 128+NTc/8): Z[nt][KSEG] fp16, Z[nt,pq] = a'[p]*o'[q].
// ---------------------------------------------------------------------------
__global__ __launch_bounds__(256) void build_CtZt(const float* __restrict__ A,
                                                  const float* __restrict__ Wa,
                                                  const float* __restrict__ ba,
                                                  const float* __restrict__ Wo,
                                                  const float* __restrict__ bo,
                                                  const float* __restrict__ actions,
                                                  const float* __restrict__ obss,
                                                  f16_t* __restrict__ Ct,
                                                  unsigned* __restrict__ Z, int n0) {
  __shared__ float Dls[PDIM][32][8];
  __shared__ float Was[PDIM][33];
  __shared__ float Wos[PDIM][33];
  __shared__ float sav[8][PDIM];
  __shared__ float sov[8][PDIM];
  const int tid = threadIdx.x;

  if (blockIdx.x < 128) {
    const int i = blockIdx.x >> 2;
    const int l0 = (blockIdx.x & 3) * 8;
    for (int e = tid; e < PDIM * 32; e += 256) {
      int p = e >> 5, j = e & 31;
      Was[p][j] = (p < 16) ? Wa[p * 32 + j] : ba[j];
      Wos[p][j] = (p < 16) ? Wo[p * 32 + j] : bo[j];
    }
    const int k = tid >> 3, lp = tid & 7;
    float Dreg[PDIM] = {};
    const float* Abase = A + (size_t)i * 32768 + k * 32 + l0 + lp;
    __syncthreads();
#pragma unroll
    for (int j = 0; j < 32; ++j) {
      float a = Abase[(size_t)j * 1024];
#pragma unroll
      for (int p = 0; p < PDIM; ++p) Dreg[p] += Was[p][j] * a;
    }
#pragma unroll
    for (int p = 0; p < PDIM; ++p) Dls[p][k][lp] = Dreg[p];
    __syncthreads();

    for (int v = tid; v < KTRUE * 8; v += 256) {
      int pq = v >> 3, l = v & 7;
      int p = pq / PDIM, q = pq % PDIM;
      float s = 0.f;
#pragma unroll
      for (int kk = 0; kk < 32; ++kk) s += Wos[q][kk] * Dls[p][kk][l];
      Ct[(size_t)(i * 32 + l0 + l) * KSEG + pq] = (f16_t)s;
    }
    for (int v = tid; v < (KSEG - KTRUE) * 8; v += 256) {
      int pq = KTRUE + (v >> 3), l = v & 7;
      Ct[(size_t)(i * 32 + l0 + l) * KSEG + pq] = (f16_t)0.f;
    }
  } else {
    const int zbid = blockIdx.x - 128;
    const int r = tid >> 5;
    const int c = tid & 31;
    const int nt = zbid * 8 + r;
    const size_t gnt = (size_t)n0 * TSTEPS + nt;
    if (c < PDIM) {
      sav[r][c] = (c < 16) ? actions[gnt * 16 + c] : 1.f;
      sov[r][c] = (c < 16) ? obss[gnt * 16 + c] : 1.f;
    }
    __syncthreads();
    unsigned* zr = Z + (size_t)nt * (KSEG / 2);
#pragma unroll
    for (int u = 0; u < 5; ++u) {
      int col = u * 32 + c;
      int k0 = col * 2, k1 = k0 + 1;
      float z0 = (k0 < KTRUE) ? sav[r][k0 / PDIM] * sov[r][k0 % PDIM] : 0.f;
      float z1 = (k1 < KTRUE) ? sav[r][k1 / PDIM] * sov[r][k1 % PDIM] : 0.f;
      unsigned short h0 = __builtin_bit_cast(unsigned short, (f16_t)z0);
      unsigned short h1 = __builtin_bit_cast(unsigned short, (f16_t)z1);
      zr[col] = (unsigned)h0 | ((unsigned)h1 << 16);
    }
  }
}

// ---------------------------------------------------------------------------
// 256x256 MFMA GEMM, 3-barrier/tile schedule (K=5 tiles: sync-light).
// Region retirement: A-sel0+B staged after barrier 1 (their readers done),
// A-sel1 staged after barrier 2. Counted vmcnt(8) once per tile.
// ---------------------------------------------------------------------------
__device__ __forceinline__ void gload16(const void* g, void* lds_) {
  __builtin_amdgcn_global_load_lds(
      (const __attribute__((address_space(1))) void*)g,
      (__attribute__((address_space(3))) void*)lds_, 16, 0, 0);
}

__global__ __launch_bounds__(512, 2) void gemm_M(const f16_t* __restrict__ Z,
                                                 const f16_t* __restrict__ Ct,
                                                 f16_t* __restrict__ Mout, int NTc) {
  __shared__ char lds[131072];
  const int nbm = NTc >> 8;
  const int nwg = nbm * 4;
  const int cpx = nwg >> 3;
  const int bid = blockIdx.x;
  const int wg = (bid & 7) * cpx + (bid >> 3);   // bijective XCD swizzle (nwg%8==0)
  const int bm = (wg >> 2) << 8;
  const int bn = (wg & 3) << 8;

  const int tid = threadIdx.x;
  const int w = tid >> 6, lane = tid & 63;
  const int wr = w >> 2, wc = w & 3;             // 2x4 wave grid
  const int lrow = lane & 15, lk = lane >> 4;
  const int u0 = lk ^ (lrow & 7);
  const int u1 = (lk + 4) ^ (lrow & 7);

  const int srow = lane >> 3;
  const int jsrc = (lane & 7) ^ srow;
  const char* Zb = (const char*)Z + (size_t)(bm + srow) * (KSEG * 2) + jsrc * 16;
  const char* Cb = (const char*)Ct + (size_t)(bn + srow) * (KSEG * 2) + jsrc * 16;

  auto stageA = [&](char* Ab, int sel, int kt) {
    const size_t ka = (size_t)kt * 128;
#pragma unroll
    for (int r = 0; r < 2; ++r) {
      int e = w * 2 + r;
      int c = sel ? (e + 8 + ((e >= 8) ? 8 : 0)) : (e + ((e >= 8) ? 8 : 0));
      gload16(Zb + (size_t)c * 8 * (KSEG * 2) + ka, Ab + c * 1024);
    }
  };
  auto stageB = [&](char* Bb, int half, int kt) {
    const size_t kb = (size_t)kt * 128;
#pragma unroll
    for (int r = 0; r < 2; ++r) {
      int c = w * 2 + r;
      gload16(Cb + (size_t)(half * 128 + c * 8) * (KSEG * 2) + kb,
              Bb + half * 16384 + c * 1024);
    }
  };

  f32x4 acc[8][4] = {};
  f16x8 af[4][2], bfr[4][2];

  // prologue: stage tiles 0 and 1
  stageA(lds, 0, 0); stageA(lds, 1, 0);
  stageB(lds + 32768, 0, 0); stageB(lds + 32768, 1, 0);
  stageA(lds + 65536, 0, 1); stageA(lds + 65536, 1, 1);
  stageB(lds + 98304, 0, 1); stageB(lds + 98304, 1, 1);
  asm volatile("s_waitcnt vmcnt(8)" ::: "memory"); SCHED0();
  SBAR(); SCHED0();

  for (int kt = 0; kt < NKT; ++kt) {
    const int c = kt & 1;
    char* Ap = lds + (c << 16);
    char* Bp = Ap + 32768;
    const bool doStage = (kt + 2 < NKT);

    // ---- half 1: read A-sel0 rows (mf0-3) + all B; barrier; stage; MFMA ----
#pragma unroll
    for (int mf = 0; mf < 4; ++mf) {
      const char* rp = Ap + (wr * 128 + mf * 16 + lrow) * 128;
      af[mf][0] = *(const f16x8*)(rp + u0 * 16);
      af[mf][1] = *(const f16x8*)(rp + u1 * 16);
    }
#pragma unroll
    for (int nf = 0; nf < 4; ++nf) {
      const char* cp = Bp + (wc * 64 + nf * 16 + lrow) * 128;
      bfr[nf][0] = *(const f16x8*)(cp + u0 * 16);
      bfr[nf][1] = *(const f16x8*)(cp + u1 * 16);
    }
    SCHED0();
    asm volatile("s_waitcnt lgkmcnt(0)" ::: "memory"); SCHED0();
    SBAR(); SCHED0();
    if (doStage) { stageA(Ap, 0, kt + 2); stageB(Bp, 0, kt + 2); stageB(Bp, 1, kt + 2); }
    PRIO(1);
#pragma unroll
    for (int ks = 0; ks < 2; ++ks)
#pragma unroll
      for (int mf = 0; mf < 4; ++mf)
#pragma unroll
        for (int nf = 0; nf < 4; ++nf)
          acc[mf][nf] = __builtin_amdgcn_mfma_f32_16x16x32_f16(af[mf][ks], bfr[nf][ks], acc[mf][nf], 0, 0, 0);
    PRIO(0);
    SCHED0();

    // ---- half 2: read A-sel1 (mf4-7); barrier; stage; MFMA ----
#pragma unroll
    for (int mf = 0; mf < 4; ++mf) {
      const char* rp = Ap + (wr * 128 + (mf + 4) * 16 + lrow) * 128;
      af[mf][0] = *(const f16x8*)(rp + u0 * 16);
      af[mf][1] = *(const f16x8*)(rp + u1 * 16);
    }
    SCHED0();
    asm volatile("s_waitcnt lgkmcnt(0)" ::: "memory"); SCHED0();
    SBAR(); SCHED0();
    if (doStage) stageA(Ap, 1, kt + 2);
    PRIO(1);
#pragma unroll
    for (int ks = 0; ks < 2; ++ks)
#pragma unroll
      for (int mf = 0; mf < 4; ++mf)
#pragma unroll
        for (int nf = 0; nf < 4; ++nf)
          acc[mf + 4][nf] = __builtin_amdgcn_mfma_f32_16x16x32_f16(af[mf][ks], bfr[nf][ks], acc[mf + 4][nf], 0, 0, 0);
    PRIO(0);

    if (kt <= NKT - 3) {
      asm volatile("s_waitcnt vmcnt(8)" ::: "memory");
    } else if (kt == NKT - 2) {
      asm volatile("s_waitcnt vmcnt(0)" ::: "memory");
    }
    SCHED0(); SBAR(); SCHED0();
  }

  // epilogue: C/D layout col=lane&15, row=(lane>>4)*4+reg (verified R2/R5)
#pragma unroll
  for (int mf = 0; mf < 8; ++mf) {
    const int row0 = bm + wr * 128 + mf * 16 + lk * 4;
#pragma unroll
    for (int nf = 0; nf < 4; ++nf) {
      const int col = bn + wc * 64 + nf * 16 + lrow;
#pragma unroll
      for (int r2 = 0; r2 < 4; ++r2)
        Mout[(size_t)(row0 + r2) * MDIM + col] = (f16_t)acc[mf][nf][r2];
    }
  }
}

// ---------------------------------------------------------------------------
// chainfin v3: transposed-chain, 5-slot / 4-deep M prefetch.
// Wave w: P_w^T = M_{15}^T*...*M_0^T via Q := Q * M_t^T; B-frag = row-major
// M_t read (b128); tiles staged by global_load_lds, graduated vmcnt.
// Finish: s = Omega^T; s = s*P_c^T (c=7..0); out = sum alpha[i]*s[i].
// ---------------------------------------------------------------------------
__global__ __launch_bounds__(512) void chainfin(const f16_t* __restrict__ M,
                                                const float* __restrict__ alpha,
                                                const float* __restrict__ Omega,
                                                float* __restrict__ out, int n0) {
  __shared__ char wbuf[8][12800];      // per wave: Q [32][80B] @0, Mbuf[5][2048] @2560
  __shared__ f16_t sPc[NCH][1024];     // chunk products P^T, row-major [32][32]
  const int wid = threadIdx.x >> 6, lane = threadIdx.x & 63;
  char* Qb = wbuf[wid];
  char* Mb5 = wbuf[wid] + 2560;
  const char* Ms = (const char*)M + ((size_t)blockIdx.x * TSTEPS + wid * CHS) * 2048;

  const int lr = lane & 15, lg = lane >> 4;

  // ---- Q init: Q = M[15]^T (reg load + one-time scatter transpose) ----
  {
    const int il = lane >> 1, c0 = (lane & 1) << 4;
    const char* mp = Ms + 15 * 2048 + il * 64 + c0 * 2;
    f16x8 va = *(const f16x8*)(mp);
    f16x8 vb = *(const f16x8*)(mp + 16);
#pragma unroll
    for (int j = 0; j < 8; ++j) {
      *(f16_t*)(Qb + (c0 + j) * 80 + il * 2) = va[j];
      *(f16_t*)(Qb + (c0 + 8 + j) * 80 + il * 2) = vb[j];
    }
  }

  // ---- staging: M-tile 2KB; dest linear, source pre-swizzled
  // swz(r) = (r + (r>>2)) & 3; LDS[row][u] = G[row][u ^ swz(row)]
  const int r0 = lane >> 2, us = lane & 3;
  const int so0 = r0 * 64 + ((us ^ ((r0 + (r0 >> 2)) & 3)) * 16);
  const int r1 = 16 + r0;
  const int so1 = r1 * 64 + ((us ^ ((r1 + (r1 >> 2)) & 3)) * 16);

  auto stageM = [&](int t) {
    const char* src = Ms + (size_t)t * 2048;
    char* dst = Mb5 + (t % 5) * 2048;
    gload16(src + so0, dst + lane * 16);
    gload16(src + so1, dst + 1024 + lane * 16);
  };

  // B-frag read offsets (swizzled): row n, unit lg ^ swz(n)
  const int bo0 = lr * 64 + ((lg ^ ((lr + (lr >> 2)) & 3)) * 16);
  const int n1 = 16 + lr;
  const int bo1 = n1 * 64 + ((lg ^ ((n1 + (n1 >> 2)) & 3)) * 16);
  const int ao0 = lr * 80 + lg * 16;
  const int ao1 = (16 + lr) * 80 + lg * 16;

  stageM(14); stageM(13); stageM(12); stageM(11);   // 4-deep prefetch

  const f32x4 z = {0.f, 0.f, 0.f, 0.f};
  for (int t = 14; t >= 0; --t) {
    // graduated counted wait: tile t ready, up to 3 tiles (6 gloads) in flight
    if (t >= 3)      { asm volatile("s_waitcnt vmcnt(6)" ::: "memory"); }
    else if (t == 2) { asm volatile("s_waitcnt vmcnt(4)" ::: "memory"); }
    else if (t == 1) { asm volatile("s_waitcnt vmcnt(2)" ::: "memory"); }
    else             { asm volatile("s_waitcnt vmcnt(0)" ::: "memory"); }
    const char* Mt = Mb5 + (t % 5) * 2048;
    f16x8 bf0 = *(const f16x8*)(Mt + bo0);
    f16x8 bf1 = *(const f16x8*)(Mt + bo1);
    f16x8 af0 = *(const f16x8*)(Qb + ao0);
    f16x8 af1 = *(const f16x8*)(Qb + ao1);
    if (t >= 4) stageM(t - 4);   // slot (t-4)%5 != t%5: no conflict with reads
    f32x4 d00 = __builtin_amdgcn_mfma_f32_16x16x32_f16(af0, bf0, z, 0, 0, 0);
    f32x4 d01 = __builtin_amdgcn_mfma_f32_16x16x32_f16(af0, bf1, z, 0, 0, 0);
    f32x4 d10 = __builtin_amdgcn_mfma_f32_16x16x32_f16(af1, bf0, z, 0, 0, 0);
    f32x4 d11 = __builtin_amdgcn_mfma_f32_16x16x32_f16(af1, bf1, z, 0, 0, 0);
    if (t > 0) {
      // write back Q: D layout col=lr, row=lg*4+r2 (+16 halves)
#pragma unroll
      for (int r2 = 0; r2 < 4; ++r2) {
        *(f16_t*)(Qb + (lg * 4 + r2) * 80 + lr * 2)             = (f16_t)d00[r2];
        *(f16_t*)(Qb + (lg * 4 + r2) * 80 + (16 + lr) * 2)      = (f16_t)d01[r2];
        *(f16_t*)(Qb + (16 + lg * 4 + r2) * 80 + lr * 2)        = (f16_t)d10[r2];
        *(f16_t*)(Qb + (16 + lg * 4 + r2) * 80 + (16 + lr) * 2) = (f16_t)d11[r2];
      }
    } else {
      f16_t* pc = sPc[wid];
#pragma unroll
      for (int r2 = 0; r2 < 4; ++r2) {
        pc[(lg * 4 + r2) * 32 + lr]           = (f16_t)d00[r2];
        pc[(lg * 4 + r2) * 32 + 16 + lr]      = (f16_t)d01[r2];
        pc[(16 + lg * 4 + r2) * 32 + lr]      = (f16_t)d10[r2];
        pc[(16 + lg * 4 + r2) * 32 + 16 + lr] = (f16_t)d11[r2];
      }
    }
  }
  __syncthreads();

  if (wid == 0) {
    const int ig = lane >> 3, lgf = lane & 7;
    float s0 = Omega[ig * 4 + 0], s1 = Omega[ig * 4 + 1];
    float s2 = Omega[ig * 4 + 2], s3 = Omega[ig * 4 + 3];
    for (int c = NCH - 1; c >= 0; --c) {
      const f16_t* pn = &sPc[c][ig * 128 + lgf * 4];
      f32x4 part = __builtin_convertvector(*(const f16x4*)(pn), f32x4) * s0;
      part += __builtin_convertvector(*(const f16x4*)(pn + 32), f32x4) * s1;
      part += __builtin_convertvector(*(const f16x4*)(pn + 64), f32x4) * s2;
      part += __builtin_convertvector(*(const f16x4*)(pn + 96), f32x4) * s3;
      float p0 = part[0], p1 = part[1], p2 = part[2], p3 = part[3];
      p0 += __shfl_down(p0, 8, 64);  p1 += __shfl_down(p1, 8, 64);
      p2 += __shfl_down(p2, 8, 64);  p3 += __shfl_down(p3, 8, 64);
      p0 += __shfl_down(p0, 16, 64); p1 += __shfl_down(p1, 16, 64);
      p2 += __shfl_down(p2, 16, 64); p3 += __shfl_down(p3, 16, 64);
      p0 += __shfl_down(p0, 32, 64); p1 += __shfl_down(p1, 32, 64);
      p2 += __shfl_down(p2, 32, 64); p3 += __shfl_down(p3, 32, 64);
      s0 = __shfl(p0, ig, 64); s1 = __shfl(p1, ig, 64);
      s2 = __shfl(p2, ig, 64); s3 = __shfl(p3, ig, 64);
    }
    float v = 0.f;
    if (lgf == 0)
      v = s0 * alpha[ig * 4 + 0] + s1 * alpha[ig * 4 + 1] +
          s2 * alpha[ig * 4 + 2] + s3 * alpha[ig * 4 + 3];
    v += __shfl_down(v, 32, 64);
    v += __shfl_down(v, 16, 64);
    v += __shfl_down(v, 8, 64);
    if (lane == 0) out[n0 + blockIdx.x] = v;
  }
}

// ---------------------------------------------------------------------------
extern "C" void kernel_launch(void* const* d_in, const int* in_sizes, int n_in,
                              void* d_out, int out_size, void* d_ws, size_t ws_size,
                              hipStream_t stream) {
  const float* actions = (const float*)d_in[0];
  const float* obss    = (const float*)d_in[1];
  const float* Wa      = (const float*)d_in[2];
  const float* ba      = (const float*)d_in[3];
  const float* Wo      = (const float*)d_in[4];
  const float* bo      = (const float*)d_in[5];
  const float* alpha   = (const float*)d_in[6];
  const float* A       = (const float*)d_in[7];
  const float* Omega   = (const float*)d_in[8];
  float* out = (float*)d_out;

  char* ws = (char*)d_ws;
  size_t fixed = ((size_t)KSEG * MDIM * 2 + 255) & ~(size_t)255;  // Ct 640KB

  int NC = NTRAJ;
  while (NC > 8) {
    size_t need = fixed + (size_t)NC * TSTEPS * ((size_t)KSEG * 2 + MDIM * 2);
    if (need <= ws_size) break;
    NC >>= 1;
  }
  const int NTc = NC * TSTEPS;
  f16_t*    Ct = (f16_t*)ws;
  unsigned* Zu = (unsigned*)(ws + fixed);
  f16_t*    M  = (f16_t*)(ws + fixed + (size_t)NTc * KSEG * 2);

  for (int n0 = 0; n0 < NTRAJ; n0 += NC) {
    hipLaunchKernelGGL(build_CtZt, dim3(128 + NTc / 8), dim3(256), 0, stream,
                       A, Wa, ba, Wo, bo, actions, obss, Ct, Zu, n0);
    hipLaunchKernelGGL(gemm_M, dim3((NTc >> 8) * 4), dim3(512), 0, stream,
                       (const f16_t*)Zu, Ct, M, NTc);
    hipLaunchKernelGGL(chainfin, dim3(NC), dim3(512), 0, stream,
                       M, alpha, Omega, out, n0);
  }
}

// Round 11
// 65.512 us; speedup vs baseline: 1.0148x; 1.0148x over previous
//
#include <hip/hip_runtime.h>

typedef _Float16 f16_t;
typedef f16_t f16x8 __attribute__((ext_vector_type(8)));
typedef f16_t f16x4 __attribute__((ext_vector_type(4)));
typedef float f32x4 __attribute__((ext_vector_type(4)));
typedef unsigned u32x4 __attribute__((ext_vector_type(4)));

#define R_ 32
#define NTRAJ 256
#define TSTEPS 128
#define PDIM 17
#define KTRUE 289
#define KSEG 320          // padded K (5 x 64)
#define NKT 5             // K-tiles
#define MDIM 1024
#define CHS 16            // steps per chain wave
#define NCH 8             // chunks per trajectory

#define SBAR() __builtin_amdgcn_s_barrier()
#define SCHED0() __builtin_amdgcn_sched_barrier(0)
#define PRIO(x) __builtin_amdgcn_s_setprio(x)

// ---------------------------------------------------------------------------
// Merged prep kernel. Blocks [0,128): Ct[il][pq] (fp16, K-contig).
// Blocks [128, 128+NTc/8): Z[nt][KSEG] fp16, Z[nt,pq] = a'[p]*o'[q].
// ---------------------------------------------------------------------------
__global__ __launch_bounds__(256) void build_CtZt(const float* __restrict__ A,
                                                  const float* __restrict__ Wa,
                                                  const float* __restrict__ ba,
                                                  const float* __restrict__ Wo,
                                                  const float* __restrict__ bo,
                                                  const float* __restrict__ actions,
                                                  const float* __restrict__ obss,
                                                  f16_t* __restrict__ Ct,
                                                  unsigned* __restrict__ Z, int n0) {
  __shared__ float Dls[PDIM][32][8];
  __shared__ float Was[PDIM][33];
  __shared__ float Wos[PDIM][33];
  __shared__ float sav[8][PDIM];
  __shared__ float sov[8][PDIM];
  const int tid = threadIdx.x;

  if (blockIdx.x < 128) {
    const int i = blockIdx.x >> 2;
    const int l0 = (blockIdx.x & 3) * 8;
    for (int e = tid; e < PDIM * 32; e += 256) {
      int p = e >> 5, j = e & 31;
      Was[p][j] = (p < 16) ? Wa[p * 32 + j] : ba[j];
      Wos[p][j] = (p < 16) ? Wo[p * 32 + j] : bo[j];
    }
    const int k = tid >> 3, lp = tid & 7;
    float Dreg[PDIM] = {};
    const float* Abase = A + (size_t)i * 32768 + k * 32 + l0 + lp;
    __syncthreads();
#pragma unroll
    for (int j = 0; j < 32; ++j) {
      float a = Abase[(size_t)j * 1024];
#pragma unroll
      for (int p = 0; p < PDIM; ++p) Dreg[p] += Was[p][j] * a;
    }
#pragma unroll
    for (int p = 0; p < PDIM; ++p) Dls[p][k][lp] = Dreg[p];
    __syncthreads();

    for (int v = tid; v < KTRUE * 8; v += 256) {
      int pq = v >> 3, l = v & 7;
      int p = pq / PDIM, q = pq % PDIM;
      float s = 0.f;
#pragma unroll
      for (int kk = 0; kk < 32; ++kk) s += Wos[q][kk] * Dls[p][kk][l];
      Ct[(size_t)(i * 32 + l0 + l) * KSEG + pq] = (f16_t)s;
    }
    for (int v = tid; v < (KSEG - KTRUE) * 8; v += 256) {
      int pq = KTRUE + (v >> 3), l = v & 7;
      Ct[(size_t)(i * 32 + l0 + l) * KSEG + pq] = (f16_t)0.f;
    }
  } else {
    const int zbid = blockIdx.x - 128;
    const int r = tid >> 5;
    const int c = tid & 31;
    const int nt = zbid * 8 + r;
    const size_t gnt = (size_t)n0 * TSTEPS + nt;
    if (c < PDIM) {
      sav[r][c] = (c < 16) ? actions[gnt * 16 + c] : 1.f;
      sov[r][c] = (c < 16) ? obss[gnt * 16 + c] : 1.f;
    }
    __syncthreads();
    unsigned* zr = Z + (size_t)nt * (KSEG / 2);
#pragma unroll
    for (int u = 0; u < 5; ++u) {
      int col = u * 32 + c;
      int k0 = col * 2, k1 = k0 + 1;
      float z0 = (k0 < KTRUE) ? sav[r][k0 / PDIM] * sov[r][k0 % PDIM] : 0.f;
      float z1 = (k1 < KTRUE) ? sav[r][k1 / PDIM] * sov[r][k1 % PDIM] : 0.f;
      unsigned short h0 = __builtin_bit_cast(unsigned short, (f16_t)z0);
      unsigned short h1 = __builtin_bit_cast(unsigned short, (f16_t)z1);
      zr[col] = (unsigned)h0 | ((unsigned)h1 << 16);
    }
  }
}

// ---------------------------------------------------------------------------
// 256x256 8-phase MFMA GEMM (REVERTED to R9-measured-best version).
// ---------------------------------------------------------------------------
__device__ __forceinline__ void gload16(const void* g, void* lds_) {
  __builtin_amdgcn_global_load_lds(
      (const __attribute__((address_space(1))) void*)g,
      (__attribute__((address_space(3))) void*)lds_, 16, 0, 0);
}

__global__ __launch_bounds__(512, 2) void gemm_M(const f16_t* __restrict__ Z,
                                                 const f16_t* __restrict__ Ct,
                                                 f16_t* __restrict__ Mout, int NTc) {
  __shared__ char lds[131072];
  const int nbm = NTc >> 8;
  const int nwg = nbm * 4;
  const int cpx = nwg >> 3;
  const int bid = blockIdx.x;
  const int wg = (bid & 7) * cpx + (bid >> 3);
  const int bm = (wg >> 2) << 8;
  const int bn = (wg & 3) << 8;

  const int tid = threadIdx.x;
  const int w = tid >> 6, lane = tid & 63;
  const int wr = w >> 2, wc = w & 3;
  const int lrow = lane & 15, lk = lane >> 4;
  const int u0 = lk ^ (lrow & 7);
  const int u1 = (lk + 4) ^ (lrow & 7);

  const int srow = lane >> 3;
  const int jsrc = (lane & 7) ^ srow;
  const char* Zb = (const char*)Z + (size_t)(bm + srow) * (KSEG * 2) + jsrc * 16;
  const char* Cb = (const char*)Ct + (size_t)(bn + srow) * (KSEG * 2) + jsrc * 16;

  auto stageA = [&](char* Ab, int sel, int kt) {
    const size_t ka = (size_t)kt * 128;
#pragma unroll
    for (int r = 0; r < 2; ++r) {
      int e = w * 2 + r;
      int c = sel ? (e + 8 + ((e >= 8) ? 8 : 0)) : (e + ((e >= 8) ? 8 : 0));
      gload16(Zb + (size_t)c * 8 * (KSEG * 2) + ka, Ab + c * 1024);
    }
  };
  auto stageB = [&](char* Bb, int half, int kt) {
    const size_t kb = (size_t)kt * 128;
#pragma unroll
    for (int r = 0; r < 2; ++r) {
      int c = w * 2 + r;
      gload16(Cb + (size_t)(half * 128 + c * 8) * (KSEG * 2) + kb,
              Bb + half * 16384 + c * 1024);
    }
  };

  f32x4 acc[8][4] = {};
  f16x8 af[4][2], bfr[4][2];

  stageA(lds, 0, 0); stageA(lds, 1, 0);
  stageB(lds + 32768, 0, 0); stageB(lds + 32768, 1, 0);
  stageA(lds + 65536, 0, 1); stageA(lds + 65536, 1, 1);
  stageB(lds + 98304, 0, 1); stageB(lds + 98304, 1, 1);
  asm volatile("s_waitcnt vmcnt(8)" ::: "memory"); SCHED0();
  SBAR(); SCHED0();

  for (int kt = 0; kt < NKT; ++kt) {
    const int p = kt & 1;
    char* Ap = lds + (p << 16);
    char* Bp = Ap + 32768;
    const bool doStage = (kt + 2 < NKT);

    // ---- P1 ----
#pragma unroll
    for (int mf = 0; mf < 4; ++mf) {
      const char* rp = Ap + (wr * 128 + mf * 16 + lrow) * 128;
      af[mf][0] = *(const f16x8*)(rp + u0 * 16);
      af[mf][1] = *(const f16x8*)(rp + u1 * 16);
    }
#pragma unroll
    for (int nf = 0; nf < 4; ++nf) {
      const char* cp = Bp + (wc * 64 + nf * 16 + lrow) * 128;
      bfr[nf][0] = *(const f16x8*)(cp + u0 * 16);
      bfr[nf][1] = *(const f16x8*)(cp + u1 * 16);
    }
    SCHED0();
    asm volatile("s_waitcnt lgkmcnt(0)" ::: "memory"); SCHED0();
    SBAR(); SCHED0();
    PRIO(1);
#pragma unroll
    for (int ks = 0; ks < 2; ++ks)
#pragma unroll
      for (int mf = 0; mf < 4; ++mf)
#pragma unroll
        for (int nf = 0; nf < 2; ++nf)
          acc[mf][nf] = __builtin_amdgcn_mfma_f32_16x16x32_f16(af[mf][ks], bfr[nf][ks], acc[mf][nf], 0, 0, 0);
    PRIO(0);
    SCHED0(); SBAR(); SCHED0();

    // ---- P2 ----
    if (doStage) { stageA(Ap, 0, kt + 2); stageB(Bp, 0, kt + 2); stageB(Bp, 1, kt + 2); }
    PRIO(1);
#pragma unroll
    for (int ks = 0; ks < 2; ++ks)
#pragma unroll
      for (int mf = 0; mf < 4; ++mf)
#pragma unroll
        for (int nf = 2; nf < 4; ++nf)
          acc[mf][nf] = __builtin_amdgcn_mfma_f32_16x16x32_f16(af[mf][ks], bfr[nf][ks], acc[mf][nf], 0, 0, 0);
    PRIO(0);
    SCHED0(); SBAR(); SCHED0();

    // ---- P3 ----
#pragma unroll
    for (int mf = 0; mf < 4; ++mf) {
      const char* rp = Ap + (wr * 128 + (mf + 4) * 16 + lrow) * 128;
      af[mf][0] = *(const f16x8*)(rp + u0 * 16);
      af[mf][1] = *(const f16x8*)(rp + u1 * 16);
    }
    SCHED0();
    asm volatile("s_waitcnt lgkmcnt(0)" ::: "memory"); SCHED0();
    SBAR(); SCHED0();
    PRIO(1);
#pragma unroll
    for (int ks = 0; ks < 2; ++ks)
#pragma unroll
      for (int mf = 0; mf < 4; ++mf)
#pragma unroll
        for (int nf = 0; nf < 2; ++nf)
          acc[mf + 4][nf] = __builtin_amdgcn_mfma_f32_16x16x32_f16(af[mf][ks], bfr[nf][ks], acc[mf + 4][nf], 0, 0, 0);
    PRIO(0);
    SCHED0(); SBAR(); SCHED0();

    // ---- P4 ----
    if (doStage) stageA(Ap, 1, kt + 2);
    PRIO(1);
#pragma unroll
    for (int ks = 0; ks < 2; ++ks)
#pragma unroll
      for (int mf = 0; mf < 4; ++mf)
#pragma unroll
        for (int nf = 2; nf < 4; ++nf)
          acc[mf + 4][nf] = __builtin_amdgcn_mfma_f32_16x16x32_f16(af[mf][ks], bfr[nf][ks], acc[mf + 4][nf], 0, 0, 0);
    PRIO(0);
    if (kt <= NKT - 3) {
      asm volatile("s_waitcnt vmcnt(8)" ::: "memory");
    } else if (kt == NKT - 2) {
      asm volatile("s_waitcnt vmcnt(0)" ::: "memory");
    }
    SCHED0(); SBAR(); SCHED0();
  }

#pragma unroll
  for (int mf = 0; mf < 8; ++mf) {
    const int row0 = bm + wr * 128 + mf * 16 + lk * 4;
#pragma unroll
    for (int nf = 0; nf < 4; ++nf) {
      const int col = bn + wc * 64 + nf * 16 + lrow;
#pragma unroll
      for (int r2 = 0; r2 < 4; ++r2)
        Mout[(size_t)(row0 + r2) * MDIM + col] = (f16_t)acc[mf][nf][r2];
    }
  }
}

// ---------------------------------------------------------------------------
// chainfin v4: register-resident chain. Wave w computes P_w = M_{t0}...M_{t0+15}
// via Y := M_t * Y (Y = running^T), t descending, Y init = I (one identity
// MFMA step, exact). A-frags = M_t rows straight from GLOBAL (3-deep reg
// prefetch, full unroll). B-frags rebuilt from D-regs via cvt_pk +
// shfl_xor(16/32) + cndmask (pi-independent: A-read & B-placement share the
// slot convention; D-layout is m89/R2/R5-verified). No LDS in the chain.
// ---------------------------------------------------------------------------
__device__ __forceinline__ unsigned packpair(float a, float b) {
  unsigned ha = (unsigned)__builtin_bit_cast(unsigned short, (f16_t)a);
  unsigned hb = (unsigned)__builtin_bit_cast(unsigned short, (f16_t)b);
  return ha | (hb << 16);
}

// dLo = D rows 0-15 (this col-half), dHi = rows 16-31. Returns B-frag (8 fp16).
__device__ __forceinline__ u32x4 exch(f32x4 dLo, f32x4 dHi, int lg) {
  unsigned p01 = packpair(dLo[0], dLo[1]);
  unsigned p23 = packpair(dLo[2], dLo[3]);
  unsigned q01 = packpair(dHi[0], dHi[1]);
  unsigned q23 = packpair(dHi[2], dHi[3]);
  unsigned rp01 = __shfl_xor(p01, 16, 64);
  unsigned rp23 = __shfl_xor(p23, 16, 64);
  unsigned rq01 = __shfl_xor(q01, 16, 64);
  unsigned rq23 = __shfl_xor(q23, 16, 64);
  const bool odd = lg & 1, hi = lg & 2;
  u32x4 P4, Q4;
  P4[0] = odd ? rp01 : p01;  P4[1] = odd ? rp23 : p23;
  P4[2] = odd ? p01 : rp01;  P4[3] = odd ? p23 : rp23;
  Q4[0] = odd ? rq01 : q01;  Q4[1] = odd ? rq23 : q23;
  Q4[2] = odd ? q01 : rq01;  Q4[3] = odd ? q23 : rq23;
  u32x4 B;
#pragma unroll
  for (int r = 0; r < 4; ++r) {
    unsigned S = __shfl_xor(P4[r], 32, 64);
    unsigned T = __shfl_xor(Q4[r], 32, 64);
    B[r] = hi ? (odd ? Q4[r] : T) : (odd ? S : P4[r]);
  }
  return B;
}

__global__ __launch_bounds__(512) void chainfin(const f16_t* __restrict__ M,
                                                const float* __restrict__ alpha,
                                                const float* __restrict__ Omega,
                                                float* __restrict__ out, int n0) {
  __shared__ f16_t sPc[NCH][1024];     // chunk products, row-major [32][32]
  const int wid = threadIdx.x >> 6, lane = threadIdx.x & 63;
  const int lr = lane & 15, lg = lane >> 4;
  const char* Ms = (const char*)M + ((size_t)blockIdx.x * TSTEPS + wid * CHS) * 2048;

  // identity B (Y = I): B0: 1 at slot 8lg+j == lr; B1: 8lg+j == 16+lr
  u32x4 B0 = {0, 0, 0, 0}, B1 = {0, 0, 0, 0};
  {
    const unsigned one = 0x3C00u;
    int j0 = lr - 8 * lg;
    if (j0 >= 0 && j0 < 8) B0[j0 >> 1] = (j0 & 1) ? (one << 16) : one;
    int j1 = 16 + lr - 8 * lg;
    if (j1 >= 0 && j1 < 8) B1[j1 >> 1] = (j1 & 1) ? (one << 16) : one;
  }

  f16x8 pA[CHS][2];
#pragma unroll
  for (int d = 0; d < 3; ++d) {                      // 3-deep prefetch
    const int t = CHS - 1 - d;
    const char* mp = Ms + (size_t)t * 2048 + lg * 16;
    pA[t][0] = *(const f16x8*)(mp + lr * 64);
    pA[t][1] = *(const f16x8*)(mp + (16 + lr) * 64);
  }

  const f32x4 z = {0.f, 0.f, 0.f, 0.f};
  f32x4 y00, y01, y10, y11;
#pragma unroll
  for (int tt = 0; tt < CHS; ++tt) {
    const int t = CHS - 1 - tt;
    if (t - 3 >= 0) {
      const char* mp = Ms + (size_t)(t - 3) * 2048 + lg * 16;
      pA[t - 3][0] = *(const f16x8*)(mp + lr * 64);
      pA[t - 3][1] = *(const f16x8*)(mp + (16 + lr) * 64);
    }
    f16x8 b0 = __builtin_bit_cast(f16x8, B0);
    f16x8 b1 = __builtin_bit_cast(f16x8, B1);
    y00 = __builtin_amdgcn_mfma_f32_16x16x32_f16(pA[t][0], b0, z, 0, 0, 0);
    y01 = __builtin_amdgcn_mfma_f32_16x16x32_f16(pA[t][0], b1, z, 0, 0, 0);
    y10 = __builtin_amdgcn_mfma_f32_16x16x32_f16(pA[t][1], b0, z, 0, 0, 0);
    y11 = __builtin_amdgcn_mfma_f32_16x16x32_f16(pA[t][1], b1, z, 0, 0, 0);
    if (tt < CHS - 1) {
      B0 = exch(y00, y10, lg);   // cols 0-15 of new Y
      B1 = exch(y01, y11, lg);   // cols 16-31
    }
  }

  // store P_w (D-layout -> row-major [32][32]), verified scatter
  {
    f16_t* pc = sPc[wid];
#pragma unroll
    for (int r2 = 0; r2 < 4; ++r2) {
      pc[(lg * 4 + r2) * 32 + lr]           = (f16_t)y00[r2];
      pc[(lg * 4 + r2) * 32 + 16 + lr]      = (f16_t)y01[r2];
      pc[(16 + lg * 4 + r2) * 32 + lr]      = (f16_t)y10[r2];
      pc[(16 + lg * 4 + r2) * 32 + 16 + lr] = (f16_t)y11[r2];
    }
  }
  __syncthreads();

  if (wid == 0) {
    const int ig = lane >> 3, lgf = lane & 7;
    float s0 = alpha[ig * 4 + 0], s1 = alpha[ig * 4 + 1];
    float s2 = alpha[ig * 4 + 2], s3 = alpha[ig * 4 + 3];
    for (int c = 0; c < NCH; ++c) {
      const f16_t* pn = &sPc[c][ig * 128 + lgf * 4];
      f32x4 part = __builtin_convertvector(*(const f16x4*)(pn), f32x4) * s0;
      part += __builtin_convertvector(*(const f16x4*)(pn + 32), f32x4) * s1;
      part += __builtin_convertvector(*(const f16x4*)(pn + 64), f32x4) * s2;
      part += __builtin_convertvector(*(const f16x4*)(pn + 96), f32x4) * s3;
      float p0 = part[0], p1 = part[1], p2 = part[2], p3 = part[3];
      p0 += __shfl_down(p0, 8, 64);  p1 += __shfl_down(p1, 8, 64);
      p2 += __shfl_down(p2, 8, 64);  p3 += __shfl_down(p3, 8, 64);
      p0 += __shfl_down(p0, 16, 64); p1 += __shfl_down(p1, 16, 64);
      p2 += __shfl_down(p2, 16, 64); p3 += __shfl_down(p3, 16, 64);
      p0 += __shfl_down(p0, 32, 64); p1 += __shfl_down(p1, 32, 64);
      p2 += __shfl_down(p2, 32, 64); p3 += __shfl_down(p3, 32, 64);
      s0 = __shfl(p0, ig, 64); s1 = __shfl(p1, ig, 64);
      s2 = __shfl(p2, ig, 64); s3 = __shfl(p3, ig, 64);
    }
    float v = 0.f;
    if (lgf == 0)
      v = s0 * Omega[ig * 4 + 0] + s1 * Omega[ig * 4 + 1] +
          s2 * Omega[ig * 4 + 2] + s3 * Omega[ig * 4 + 3];
    v += __shfl_down(v, 32, 64);
    v += __shfl_down(v, 16, 64);
    v += __shfl_down(v, 8, 64);
    if (lane == 0) out[n0 + blockIdx.x] = v;
  }
}

// ---------------------------------------------------------------------------
extern "C" void kernel_launch(void* const* d_in, const int* in_sizes, int n_in,
                              void* d_out, int out_size, void* d_ws, size_t ws_size,
                              hipStream_t stream) {
  const float* actions = (const float*)d_in[0];
  const float* obss    = (const float*)d_in[1];
  const float* Wa      = (const float*)d_in[2];
  const float* ba      = (const float*)d_in[3];
  const float* Wo      = (const float*)d_in[4];
  const float* bo      = (const float*)d_in[5];
  const float* alpha   = (const float*)d_in[6];
  const float* A       = (const float*)d_in[7];
  const float* Omega   = (const float*)d_in[8];
  float* out = (float*)d_out;

  char* ws = (char*)d_ws;
  size_t fixed = ((size_t)KSEG * MDIM * 2 + 255) & ~(size_t)255;  // Ct 640KB

  int NC = NTRAJ;
  while (NC > 8) {
    size_t need = fixed + (size_t)NC * TSTEPS * ((size_t)KSEG * 2 + MDIM * 2);
    if (need <= ws_size) break;
    NC >>= 1;
  }
  const int NTc = NC * TSTEPS;
  f16_t*    Ct = (f16_t*)ws;
  unsigned* Zu = (unsigned*)(ws + fixed);
  f16_t*    M  = (f16_t*)(ws + fixed + (size_t)NTc * KSEG * 2);

  for (int n0 = 0; n0 < NTRAJ; n0 += NC) {
    hipLaunchKernelGGL(build_CtZt, dim3(128 + NTc / 8), dim3(256), 0, stream,
                       A, Wa, ba, Wo, bo, actions, obss, Ct, Zu, n0);
    hipLaunchKernelGGL(gemm_M, dim3((NTc >> 8) * 4), dim3(512), 0, stream,
                       (const f16_t*)Zu, Ct, M, NTc);
    hipLaunchKernelGGL(chainfin, dim3(NC), dim3(512), 0, stream,
                       M, alpha, Omega, out, n0);
  }
}

// Round 12
// 63.560 us; speedup vs baseline: 1.0460x; 1.0307x over previous
//
#include <hip/hip_runtime.h>

typedef _Float16 f16_t;
typedef f16_t f16x8 __attribute__((ext_vector_type(8)));
typedef f16_t f16x4 __attribute__((ext_vector_type(4)));
typedef float f32x4 __attribute__((ext_vector_type(4)));

#define R_ 32
#define NTRAJ 256
#define TSTEPS 128
#define PDIM 17
#define KTRUE 289
#define KSEG 320          // padded K (5 x 64)
#define NKT 5             // K-tiles
#define MDIM 1024
#define CHS 16            // steps per chain wave
#define NCH 8             // chunks per trajectory

#define SBAR() __builtin_amdgcn_s_barrier()
#define SCHED0() __builtin_amdgcn_sched_barrier(0)
#define PRIO(x) __builtin_amdgcn_s_setprio(x)

// ---------------------------------------------------------------------------
// Merged prep kernel. Blocks [0,128): Ct[il][pq] (fp16, K-contig).
// Blocks [128, 128+NTc/8): Z[nt][KSEG] fp16, Z[nt,pq] = a'[p]*o'[q].
// ---------------------------------------------------------------------------
__global__ __launch_bounds__(256) void build_CtZt(const float* __restrict__ A,
                                                  const float* __restrict__ Wa,
                                                  const float* __restrict__ ba,
                                                  const float* __restrict__ Wo,
                                                  const float* __restrict__ bo,
                                                  const float* __restrict__ actions,
                                                  const float* __restrict__ obss,
                                                  f16_t* __restrict__ Ct,
                                                  unsigned* __restrict__ Z, int n0) {
  __shared__ float Dls[PDIM][32][8];
  __shared__ float Was[PDIM][33];
  __shared__ float Wos[PDIM][33];
  __shared__ float sav[8][PDIM];
  __shared__ float sov[8][PDIM];
  const int tid = threadIdx.x;

  if (blockIdx.x < 128) {
    const int i = blockIdx.x >> 2;
    const int l0 = (blockIdx.x & 3) * 8;
    for (int e = tid; e < PDIM * 32; e += 256) {
      int p = e >> 5, j = e & 31;
      Was[p][j] = (p < 16) ? Wa[p * 32 + j] : ba[j];
      Wos[p][j] = (p < 16) ? Wo[p * 32 + j] : bo[j];
    }
    const int k = tid >> 3, lp = tid & 7;
    float Dreg[PDIM] = {};
    const float* Abase = A + (size_t)i * 32768 + k * 32 + l0 + lp;
    __syncthreads();
#pragma unroll
    for (int j = 0; j < 32; ++j) {
      float a = Abase[(size_t)j * 1024];
#pragma unroll
      for (int p = 0; p < PDIM; ++p) Dreg[p] += Was[p][j] * a;
    }
#pragma unroll
    for (int p = 0; p < PDIM; ++p) Dls[p][k][lp] = Dreg[p];
    __syncthreads();

    for (int v = tid; v < KTRUE * 8; v += 256) {
      int pq = v >> 3, l = v & 7;
      int p = pq / PDIM, q = pq % PDIM;
      float s = 0.f;
#pragma unroll
      for (int kk = 0; kk < 32; ++kk) s += Wos[q][kk] * Dls[p][kk][l];
      Ct[(size_t)(i * 32 + l0 + l) * KSEG + pq] = (f16_t)s;
    }
    for (int v = tid; v < (KSEG - KTRUE) * 8; v += 256) {
      int pq = KTRUE + (v >> 3), l = v & 7;
      Ct[(size_t)(i * 32 + l0 + l) * KSEG + pq] = (f16_t)0.f;
    }
  } else {
    const int zbid = blockIdx.x - 128;
    const int r = tid >> 5;
    const int c = tid & 31;
    const int nt = zbid * 8 + r;
    const size_t gnt = (size_t)n0 * TSTEPS + nt;
    if (c < PDIM) {
      sav[r][c] = (c < 16) ? actions[gnt * 16 + c] : 1.f;
      sov[r][c] = (c < 16) ? obss[gnt * 16 + c] : 1.f;
    }
    __syncthreads();
    unsigned* zr = Z + (size_t)nt * (KSEG / 2);
#pragma unroll
    for (int u = 0; u < 5; ++u) {
      int col = u * 32 + c;
      int k0 = col * 2, k1 = k0 + 1;
      float z0 = (k0 < KTRUE) ? sav[r][k0 / PDIM] * sov[r][k0 % PDIM] : 0.f;
      float z1 = (k1 < KTRUE) ? sav[r][k1 / PDIM] * sov[r][k1 % PDIM] : 0.f;
      unsigned short h0 = __builtin_bit_cast(unsigned short, (f16_t)z0);
      unsigned short h1 = __builtin_bit_cast(unsigned short, (f16_t)z1);
      zr[col] = (unsigned)h0 | ((unsigned)h1 << 16);
    }
  }
}

// ---------------------------------------------------------------------------
// 256x256 8-phase MFMA GEMM (R9-best structure; SCHED0 kept only after
// waitcnt asm per rule 18 — decorative fences removed).
// ---------------------------------------------------------------------------
__device__ __forceinline__ void gload16(const void* g, void* lds_) {
  __builtin_amdgcn_global_load_lds(
      (const __attribute__((address_space(1))) void*)g,
      (__attribute__((address_space(3))) void*)lds_, 16, 0, 0);
}

__global__ __launch_bounds__(512, 2) void gemm_M(const f16_t* __restrict__ Z,
                                                 const f16_t* __restrict__ Ct,
                                                 f16_t* __restrict__ Mout, int NTc) {
  __shared__ char lds[131072];
  const int nbm = NTc >> 8;
  const int nwg = nbm * 4;
  const int cpx = nwg >> 3;
  const int bid = blockIdx.x;
  const int wg = (bid & 7) * cpx + (bid >> 3);   // bijective XCD swizzle (nwg%8==0)
  const int bm = (wg >> 2) << 8;
  const int bn = (wg & 3) << 8;

  const int tid = threadIdx.x;
  const int w = tid >> 6, lane = tid & 63;
  const int wr = w >> 2, wc = w & 3;
  const int lrow = lane & 15, lk = lane >> 4;
  const int u0 = lk ^ (lrow & 7);
  const int u1 = (lk + 4) ^ (lrow & 7);

  const int srow = lane >> 3;
  const int jsrc = (lane & 7) ^ srow;
  const char* Zb = (const char*)Z + (size_t)(bm + srow) * (KSEG * 2) + jsrc * 16;
  const char* Cb = (const char*)Ct + (size_t)(bn + srow) * (KSEG * 2) + jsrc * 16;

  auto stageA = [&](char* Ab, int sel, int kt) {
    const size_t ka = (size_t)kt * 128;
#pragma unroll
    for (int r = 0; r < 2; ++r) {
      int e = w * 2 + r;
      int c = sel ? (e + 8 + ((e >= 8) ? 8 : 0)) : (e + ((e >= 8) ? 8 : 0));
      gload16(Zb + (size_t)c * 8 * (KSEG * 2) + ka, Ab + c * 1024);
    }
  };
  auto stageB = [&](char* Bb, int half, int kt) {
    const size_t kb = (size_t)kt * 128;
#pragma unroll
    for (int r = 0; r < 2; ++r) {
      int c = w * 2 + r;
      gload16(Cb + (size_t)(half * 128 + c * 8) * (KSEG * 2) + kb,
              Bb + half * 16384 + c * 1024);
    }
  };

  f32x4 acc[8][4] = {};
  f16x8 af[4][2], bfr[4][2];

  stageA(lds, 0, 0); stageA(lds, 1, 0);
  stageB(lds + 32768, 0, 0); stageB(lds + 32768, 1, 0);
  stageA(lds + 65536, 0, 1); stageA(lds + 65536, 1, 1);
  stageB(lds + 98304, 0, 1); stageB(lds + 98304, 1, 1);
  asm volatile("s_waitcnt vmcnt(8)" ::: "memory"); SCHED0();
  SBAR();

  for (int kt = 0; kt < NKT; ++kt) {
    const int p = kt & 1;
    char* Ap = lds + (p << 16);
    char* Bp = Ap + 32768;
    const bool doStage = (kt + 2 < NKT);

    // ---- P1: ds_read A-quarter0 (mf0-3) + B-all; lgkm before barrier ----
#pragma unroll
    for (int mf = 0; mf < 4; ++mf) {
      const char* rp = Ap + (wr * 128 + mf * 16 + lrow) * 128;
      af[mf][0] = *(const f16x8*)(rp + u0 * 16);
      af[mf][1] = *(const f16x8*)(rp + u1 * 16);
    }
#pragma unroll
    for (int nf = 0; nf < 4; ++nf) {
      const char* cp = Bp + (wc * 64 + nf * 16 + lrow) * 128;
      bfr[nf][0] = *(const f16x8*)(cp + u0 * 16);
      bfr[nf][1] = *(const f16x8*)(cp + u1 * 16);
    }
    asm volatile("s_waitcnt lgkmcnt(0)" ::: "memory"); SCHED0();
    SBAR();
    PRIO(1);
#pragma unroll
    for (int ks = 0; ks < 2; ++ks)
#pragma unroll
      for (int mf = 0; mf < 4; ++mf)
#pragma unroll
        for (int nf = 0; nf < 2; ++nf)
          acc[mf][nf] = __builtin_amdgcn_mfma_f32_16x16x32_f16(af[mf][ks], bfr[nf][ks], acc[mf][nf], 0, 0, 0);
    PRIO(0);
    SBAR();

    // ---- P2: stage tile kt+2 A-sel0 + B-both into buffer p (retired) ----
    if (doStage) { stageA(Ap, 0, kt + 2); stageB(Bp, 0, kt + 2); stageB(Bp, 1, kt + 2); }
    PRIO(1);
#pragma unroll
    for (int ks = 0; ks < 2; ++ks)
#pragma unroll
      for (int mf = 0; mf < 4; ++mf)
#pragma unroll
        for (int nf = 2; nf < 4; ++nf)
          acc[mf][nf] = __builtin_amdgcn_mfma_f32_16x16x32_f16(af[mf][ks], bfr[nf][ks], acc[mf][nf], 0, 0, 0);
    PRIO(0);
    SBAR();

    // ---- P3: ds_read A-quarter1 (mf4-7); lgkm before barrier ----
#pragma unroll
    for (int mf = 0; mf < 4; ++mf) {
      const char* rp = Ap + (wr * 128 + (mf + 4) * 16 + lrow) * 128;
      af[mf][0] = *(const f16x8*)(rp + u0 * 16);
      af[mf][1] = *(const f16x8*)(rp + u1 * 16);
    }
    asm volatile("s_waitcnt lgkmcnt(0)" ::: "memory"); SCHED0();
    SBAR();
    PRIO(1);
#pragma unroll
    for (int ks = 0; ks < 2; ++ks)
#pragma unroll
      for (int mf = 0; mf < 4; ++mf)
#pragma unroll
        for (int nf = 0; nf < 2; ++nf)
          acc[mf + 4][nf] = __builtin_amdgcn_mfma_f32_16x16x32_f16(af[mf][ks], bfr[nf][ks], acc[mf + 4][nf], 0, 0, 0);
    PRIO(0);
    SBAR();

    // ---- P4: stage tile kt+2 A-sel1 into buffer p; counted vmcnt gate ----
    if (doStage) stageA(Ap, 1, kt + 2);
    PRIO(1);
#pragma unroll
    for (int ks = 0; ks < 2; ++ks)
#pragma unroll
      for (int mf = 0; mf < 4; ++mf)
#pragma unroll
        for (int nf = 2; nf < 4; ++nf)
          acc[mf + 4][nf] = __builtin_amdgcn_mfma_f32_16x16x32_f16(af[mf][ks], bfr[nf][ks], acc[mf + 4][nf], 0, 0, 0);
    PRIO(0);
    if (kt <= NKT - 3) {
      asm volatile("s_waitcnt vmcnt(8)" ::: "memory");
    } else if (kt == NKT - 2) {
      asm volatile("s_waitcnt vmcnt(0)" ::: "memory");
    }
    SCHED0();
    SBAR();
  }

  // epilogue: C/D layout col=lane&15, row=(lane>>4)*4+reg (verified R2/R5)
#pragma unroll
  for (int mf = 0; mf < 8; ++mf) {
    const int row0 = bm + wr * 128 + mf * 16 + lk * 4;
#pragma unroll
    for (int nf = 0; nf < 4; ++nf) {
      const int col = bn + wc * 64 + nf * 16 + lrow;
#pragma unroll
      for (int r2 = 0; r2 < 4; ++r2)
        Mout[(size_t)(row0 + r2) * MDIM + col] = (f16_t)acc[mf][nf][r2];
    }
  }
}

// ---------------------------------------------------------------------------
// chainfin v2 (R9-measured-best): transposed-chain, 3-slot triple buffer.
// Wave w: P_w^T = M_{15}^T*...*M_0^T via Q := Q * M_t^T; B-frag = row-major
// M_t read (b128) from LDS staged by global_load_lds; per-wave vmcnt(2).
// Finish: s = Omega^T; s = s*P_c^T (c=7..0); out = sum alpha[i]*s[i].
// ---------------------------------------------------------------------------
__global__ __launch_bounds__(512) void chainfin(const f16_t* __restrict__ M,
                                                const float* __restrict__ alpha,
                                                const float* __restrict__ Omega,
                                                float* __restrict__ out, int n0) {
  __shared__ char wbuf[8][8704];       // per wave: Q [32][80B] @0, Mbuf[3][2048] @2560
  __shared__ f16_t sPc[NCH][1024];     // chunk products P^T, row-major [32][32]
  const int wid = threadIdx.x >> 6, lane = threadIdx.x & 63;
  char* Qb = wbuf[wid];
  char* Mb3 = wbuf[wid] + 2560;
  const char* Ms = (const char*)M + ((size_t)blockIdx.x * TSTEPS + wid * CHS) * 2048;

  const int lr = lane & 15, lg = lane >> 4;

  // ---- Q init: Q = M[15]^T (reg load + one-time scatter transpose) ----
  {
    const int il = lane >> 1, c0 = (lane & 1) << 4;
    const char* mp = Ms + 15 * 2048 + il * 64 + c0 * 2;
    f16x8 va = *(const f16x8*)(mp);
    f16x8 vb = *(const f16x8*)(mp + 16);
#pragma unroll
    for (int j = 0; j < 8; ++j) {
      *(f16_t*)(Qb + (c0 + j) * 80 + il * 2) = va[j];
      *(f16_t*)(Qb + (c0 + 8 + j) * 80 + il * 2) = vb[j];
    }
  }

  // ---- staging: M-tile 2KB; dest linear, source pre-swizzled
  // swz(r) = (r + (r>>2)) & 3; LDS[row][u] = G[row][u ^ swz(row)]
  const int r0 = lane >> 2, us = lane & 3;
  const int so0 = r0 * 64 + ((us ^ ((r0 + (r0 >> 2)) & 3)) * 16);
  const int r1 = 16 + r0;
  const int so1 = r1 * 64 + ((us ^ ((r1 + (r1 >> 2)) & 3)) * 16);

  auto stageM = [&](int t) {
    const char* src = Ms + (size_t)t * 2048;
    char* dst = Mb3 + (t % 3) * 2048;
    gload16(src + so0, dst + lane * 16);
    gload16(src + so1, dst + 1024 + lane * 16);
  };

  // B-frag read offsets (swizzled): row n, unit lg ^ swz(n)
  const int bo0 = lr * 64 + ((lg ^ ((lr + (lr >> 2)) & 3)) * 16);
  const int n1 = 16 + lr;
  const int bo1 = n1 * 64 + ((lg ^ ((n1 + (n1 >> 2)) & 3)) * 16);
  const int ao0 = lr * 80 + lg * 16;
  const int ao1 = (16 + lr) * 80 + lg * 16;

  stageM(14); stageM(13);   // 2-deep prefetch (4 outstanding)

  const f32x4 z = {0.f, 0.f, 0.f, 0.f};
  for (int t = 14; t >= 0; --t) {
    if (t > 0) { asm volatile("s_waitcnt vmcnt(2)" ::: "memory"); }
    else       { asm volatile("s_waitcnt vmcnt(0)" ::: "memory"); }
    const char* Mt = Mb3 + (t % 3) * 2048;
    f16x8 bf0 = *(const f16x8*)(Mt + bo0);
    f16x8 bf1 = *(const f16x8*)(Mt + bo1);
    f16x8 af0 = *(const f16x8*)(Qb + ao0);
    f16x8 af1 = *(const f16x8*)(Qb + ao1);
    if (t >= 2) stageM(t - 2);
    f32x4 d00 = __builtin_amdgcn_mfma_f32_16x16x32_f16(af0, bf0, z, 0, 0, 0);
    f32x4 d01 = __builtin_amdgcn_mfma_f32_16x16x32_f16(af0, bf1, z, 0, 0, 0);
    f32x4 d10 = __builtin_amdgcn_mfma_f32_16x16x32_f16(af1, bf0, z, 0, 0, 0);
    f32x4 d11 = __builtin_amdgcn_mfma_f32_16x16x32_f16(af1, bf1, z, 0, 0, 0);
    if (t > 0) {
      // write back Q: D layout col=lr, row=lg*4+r2 (+16 halves)
#pragma unroll
      for (int r2 = 0; r2 < 4; ++r2) {
        *(f16_t*)(Qb + (lg * 4 + r2) * 80 + lr * 2)             = (f16_t)d00[r2];
        *(f16_t*)(Qb + (lg * 4 + r2) * 80 + (16 + lr) * 2)      = (f16_t)d01[r2];
        *(f16_t*)(Qb + (16 + lg * 4 + r2) * 80 + lr * 2)        = (f16_t)d10[r2];
        *(f16_t*)(Qb + (16 + lg * 4 + r2) * 80 + (16 + lr) * 2) = (f16_t)d11[r2];
      }
    } else {
      f16_t* pc = sPc[wid];
#pragma unroll
      for (int r2 = 0; r2 < 4; ++r2) {
        pc[(lg * 4 + r2) * 32 + lr]           = (f16_t)d00[r2];
        pc[(lg * 4 + r2) * 32 + 16 + lr]      = (f16_t)d01[r2];
        pc[(16 + lg * 4 + r2) * 32 + lr]      = (f16_t)d10[r2];
        pc[(16 + lg * 4 + r2) * 32 + 16 + lr] = (f16_t)d11[r2];
      }
    }
  }
  __syncthreads();

  if (wid == 0) {
    const int ig = lane >> 3, lgf = lane & 7;
    float s0 = Omega[ig * 4 + 0], s1 = Omega[ig * 4 + 1];
    float s2 = Omega[ig * 4 + 2], s3 = Omega[ig * 4 + 3];
    for (int c = NCH - 1; c >= 0; --c) {
      const f16_t* pn = &sPc[c][ig * 128 + lgf * 4];
      f32x4 part = __builtin_convertvector(*(const f16x4*)(pn), f32x4) * s0;
      part += __builtin_convertvector(*(const f16x4*)(pn + 32), f32x4) * s1;
      part += __builtin_convertvector(*(const f16x4*)(pn + 64), f32x4) * s2;
      part += __builtin_convertvector(*(const f16x4*)(pn + 96), f32x4) * s3;
      float p0 = part[0], p1 = part[1], p2 = part[2], p3 = part[3];
      p0 += __shfl_down(p0, 8, 64);  p1 += __shfl_down(p1, 8, 64);
      p2 += __shfl_down(p2, 8, 64);  p3 += __shfl_down(p3, 8, 64);
      p0 += __shfl_down(p0, 16, 64); p1 += __shfl_down(p1, 16, 64);
      p2 += __shfl_down(p2, 16, 64); p3 += __shfl_down(p3, 16, 64);
      p0 += __shfl_down(p0, 32, 64); p1 += __shfl_down(p1, 32, 64);
      p2 += __shfl_down(p2, 32, 64); p3 += __shfl_down(p3, 32, 64);
      s0 = __shfl(p0, ig, 64); s1 = __shfl(p1, ig, 64);
      s2 = __shfl(p2, ig, 64); s3 = __shfl(p3, ig, 64);
    }
    float v = 0.f;
    if (lgf == 0)
      v = s0 * alpha[ig * 4 + 0] + s1 * alpha[ig * 4 + 1] +
          s2 * alpha[ig * 4 + 2] + s3 * alpha[ig * 4 + 3];
    v += __shfl_down(v, 32, 64);
    v += __shfl_down(v, 16, 64);
    v += __shfl_down(v, 8, 64);
    if (lane == 0) out[n0 + blockIdx.x] = v;
  }
}

// ---------------------------------------------------------------------------
extern "C" void kernel_launch(void* const* d_in, const int* in_sizes, int n_in,
                              void* d_out, int out_size, void* d_ws, size_t ws_size,
                              hipStream_t stream) {
  const float* actions = (const float*)d_in[0];
  const float* obss    = (const float*)d_in[1];
  const float* Wa      = (const float*)d_in[2];
  const float* ba      = (const float*)d_in[3];
  const float* Wo      = (const float*)d_in[4];
  const float* bo      = (const float*)d_in[5];
  const float* alpha   = (const float*)d_in[6];
  const float* A       = (const float*)d_in[7];
  const float* Omega   = (const float*)d_in[8];
  float* out = (float*)d_out;

  char* ws = (char*)d_ws;
  size_t fixed = ((size_t)KSEG * MDIM * 2 + 255) & ~(size_t)255;  // Ct 640KB

  int NC = NTRAJ;
  while (NC > 8) {
    size_t need = fixed + (size_t)NC * TSTEPS * ((size_t)KSEG * 2 + MDIM * 2);
    if (need <= ws_size) break;
    NC >>= 1;
  }
  const int NTc = NC * TSTEPS;
  f16_t*    Ct = (f16_t*)ws;
  unsigned* Zu = (unsigned*)(ws + fixed);
  f16_t*    M  = (f16_t*)(ws + fixed + (size_t)NTc * KSEG * 2);

  for (int n0 = 0; n0 < NTRAJ; n0 += NC) {
    hipLaunchKernelGGL(build_CtZt, dim3(128 + NTc / 8), dim3(256), 0, stream,
                       A, Wa, ba, Wo, bo, actions, obss, Ct, Zu, n0);
    hipLaunchKernelGGL(gemm_M, dim3((NTc >> 8) * 4), dim3(512), 0, stream,
                       (const f16_t*)Zu, Ct, M, NTc);
    hipLaunchKernelGGL(chainfin, dim3(NC), dim3(512), 0, stream,
                       M, alpha, Omega, out, n0);
  }
}